// Round 14
// baseline (523.802 us; speedup 1.0000x reference)
//
#include <hip/hip_runtime.h>

#define D 128
#define NSHARD 8
typedef unsigned short u16;
typedef unsigned int u32;
typedef __attribute__((ext_vector_type(8))) short short8;
typedef __attribute__((ext_vector_type(16))) float float16;

__device__ __forceinline__ u16 f2bf(float f) {
    u32 u = __builtin_bit_cast(u32, f);
    u += 0x7FFFu + ((u >> 16) & 1u);   // round-to-nearest-even
    return (u16)(u >> 16);
}
__device__ __forceinline__ float bf2f(u16 b) {
    return __builtin_bit_cast(float, ((u32)b) << 16);
}
__device__ __forceinline__ short8 zero8() {
    short8 z;
    #pragma unroll
    for (int i = 0; i < 8; ++i) z[i] = 0;
    return z;
}

// ---------------- CSR build ----------------

// Fused: XCD-sharded histogram (+rank) for blocks [0,nblkA); fp32->bf16 convert
// for blocks [nblkA, nblkA+nblkB). Shard = blockIdx&7 keeps each atomic's target
// line in one XCD's L2 (no cross-XCD migration); hist's idle VALU/BW hides the
// convert. rank[e] is the SHARD-LOCAL rank; fill adds off[shard][d].
__global__ __launch_bounds__(256) void hist_tobf16_kernel(
        const int* __restrict__ dst, int* __restrict__ cntS,
        int* __restrict__ rank, int E, int N, int nblkA,
        const float* __restrict__ xin, u16* __restrict__ xb, int n8) {
    if ((int)blockIdx.x < nblkA) {
        const int e = blockIdx.x * 256 + threadIdx.x;
        if (e < E) {
            const int shard = blockIdx.x & (NSHARD - 1);
            rank[e] = atomicAdd(&cntS[(size_t)shard * N + dst[e]], 1);
        }
    } else {
        const int i = (blockIdx.x - nblkA) * 256 + threadIdx.x;
        if (i < n8) {
            float4 a = *reinterpret_cast<const float4*>(xin + (size_t)i * 8);
            float4 b = *reinterpret_cast<const float4*>(xin + (size_t)i * 8 + 4);
            short8 r;
            r[0] = (short)f2bf(a.x); r[1] = (short)f2bf(a.y);
            r[2] = (short)f2bf(a.z); r[3] = (short)f2bf(a.w);
            r[4] = (short)f2bf(b.x); r[5] = (short)f2bf(b.y);
            r[6] = (short)f2bf(b.z); r[7] = (short)f2bf(b.w);
            *reinterpret_cast<short8*>(xb + (size_t)i * 8) = r;
        }
    }
}

// per-node shard prefix: off[s][d] = sum of cntS[s'<s][d]; cnttot[d] = degree;
// invd = 1/max(deg,1). All reads/writes coalesced across threads.
__global__ __launch_bounds__(256) void shardoff_kernel(
        const int* __restrict__ cntS, int* __restrict__ off,
        int* __restrict__ cnttot, float* __restrict__ invd, int N) {
    const int d = blockIdx.x * 256 + threadIdx.x;
    if (d >= N) return;
    int run = 0;
    #pragma unroll
    for (int s = 0; s < NSHARD; ++s) {
        const int c = cntS[(size_t)s * N + d];
        off[(size_t)s * N + d] = run;
        run += c;
    }
    cnttot[d] = run;
    invd[d] = 1.0f / (float)(run > 1 ? run : 1);
}

__global__ __launch_bounds__(256) void scan1_kernel(const int* __restrict__ cnt,
        int* __restrict__ rowptr, int* __restrict__ blksum, int N) {
    __shared__ int sdata[256];
    const int base = blockIdx.x * 1024 + threadIdx.x * 4;
    int v0 = 0, v1 = 0, v2 = 0, v3 = 0;
    if (base + 3 < N) {
        int4 q = *reinterpret_cast<const int4*>(cnt + base);
        v0 = q.x; v1 = q.y; v2 = q.z; v3 = q.w;
    } else {
        if (base + 0 < N) v0 = cnt[base + 0];
        if (base + 1 < N) v1 = cnt[base + 1];
        if (base + 2 < N) v2 = cnt[base + 2];
    }
    const int t = v0 + v1 + v2 + v3;
    int val = t;
    sdata[threadIdx.x] = val;
    __syncthreads();
    for (int off = 1; off < 256; off <<= 1) {
        int other = (threadIdx.x >= off) ? sdata[threadIdx.x - off] : 0;
        __syncthreads();
        val += other;
        sdata[threadIdx.x] = val;
        __syncthreads();
    }
    const int excl = val - t;
    if (base + 0 < N) rowptr[base + 0] = excl;
    if (base + 1 < N) rowptr[base + 1] = excl + v0;
    if (base + 2 < N) rowptr[base + 2] = excl + v0 + v1;
    if (base + 3 < N) rowptr[base + 3] = excl + v0 + v1 + v2;
    if (threadIdx.x == 255) blksum[blockIdx.x] = val;
}

// parallel scan over <=256 block sums, single block
__global__ __launch_bounds__(256) void scan2_kernel(int* __restrict__ blksum, int nb) {
    __shared__ int s[256];
    const int t = threadIdx.x;
    const int v = (t < nb) ? blksum[t] : 0;
    int val = v;
    s[t] = val;
    __syncthreads();
    for (int off = 1; off < 256; off <<= 1) {
        int o = (t >= off) ? s[t - off] : 0;
        __syncthreads();
        val += o;
        s[t] = val;
        __syncthreads();
    }
    if (t < nb) blksum[t] = val - v;   // exclusive
    if (t == 255) blksum[nb] = val;    // grand total
}

__global__ __launch_bounds__(256) void scan3_kernel(int* __restrict__ rowptr,
        const int* __restrict__ blksum, int N) {
    const int base = blockIdx.x * 1024 + threadIdx.x * 4;
    const int off = blksum[blockIdx.x];
    #pragma unroll
    for (int k = 0; k < 4; ++k)
        if (base + k < N) rowptr[base + k] += off;
    if (base == 0 && blockIdx.x == 0) rowptr[N] = blksum[gridDim.x];
}

// atomic-free fill: position = rowptr[dst] + shard prefix + shard-local rank.
// Edge e was histogrammed by block e>>8, i.e. shard (e>>8)&7.
__global__ __launch_bounds__(256) void fill_kernel(const int* __restrict__ src,
        const int* __restrict__ dst, const int* __restrict__ rowptr,
        const int* __restrict__ off, const int* __restrict__ rank,
        int* __restrict__ colidx, int E, int N) {
    const int e = blockIdx.x * 256 + threadIdx.x;
    if (e < E) {
        const int d = dst[e];
        const int shard = (e >> 8) & (NSHARD - 1);
        colidx[rowptr[d] + off[(size_t)shard * N + d] + rank[e]] = src[e];
    }
}

// ---------------- gather mean, 128-wide rows (bf16) ----------------
__global__ __launch_bounds__(256) void gather_kernel(const u16* __restrict__ xin,
        const int* __restrict__ rowptr, const int* __restrict__ colidx,
        const float* __restrict__ invd, u16* __restrict__ outA, int N) {
    const int node = blockIdx.x * 4 + (threadIdx.x >> 6);
    if (node >= N) return;
    const int lane = threadIdx.x & 63;
    const int g = lane >> 4;          // edge subgroup 0..3
    const int r = lane & 15;          // col group: bf16 cols [r*8, r*8+8)
    const int beg = rowptr[node];
    const int nb = rowptr[node + 1] - beg;

    float a0 = 0.f, a1 = 0.f, a2 = 0.f, a3 = 0.f;
    float a4 = 0.f, a5 = 0.f, a6 = 0.f, a7 = 0.f;

    for (int base = 0; base < nb; base += 8) {
        const bool p0 = (base + g) < nb;
        const bool p1 = (base + 4 + g) < nb;
        uint4 v0 = make_uint4(0, 0, 0, 0), v1 = v0;
        if (p0) {
            int s0 = colidx[beg + base + g];
            v0 = *reinterpret_cast<const uint4*>(xin + (size_t)s0 * D + r * 8);
        }
        if (p1) {
            int s1 = colidx[beg + base + 4 + g];
            v1 = *reinterpret_cast<const uint4*>(xin + (size_t)s1 * D + r * 8);
        }
        a0 += bf2f((u16)v0.x) + bf2f((u16)v1.x);
        a1 += bf2f((u16)(v0.x >> 16)) + bf2f((u16)(v1.x >> 16));
        a2 += bf2f((u16)v0.y) + bf2f((u16)v1.y);
        a3 += bf2f((u16)(v0.y >> 16)) + bf2f((u16)(v1.y >> 16));
        a4 += bf2f((u16)v0.z) + bf2f((u16)v1.z);
        a5 += bf2f((u16)(v0.z >> 16)) + bf2f((u16)(v1.z >> 16));
        a6 += bf2f((u16)v0.w) + bf2f((u16)v1.w);
        a7 += bf2f((u16)(v0.w >> 16)) + bf2f((u16)(v1.w >> 16));
    }

    #pragma unroll
    for (int m = 16; m <= 32; m <<= 1) {
        a0 += __shfl_xor(a0, m, 64); a1 += __shfl_xor(a1, m, 64);
        a2 += __shfl_xor(a2, m, 64); a3 += __shfl_xor(a3, m, 64);
        a4 += __shfl_xor(a4, m, 64); a5 += __shfl_xor(a5, m, 64);
        a6 += __shfl_xor(a6, m, 64); a7 += __shfl_xor(a7, m, 64);
    }

    if (g == 0) {
        const float ic = invd[node];
        uint4 o;
        o.x = (u32)f2bf(a0 * ic) | ((u32)f2bf(a1 * ic) << 16);
        o.y = (u32)f2bf(a2 * ic) | ((u32)f2bf(a3 * ic) << 16);
        o.z = (u32)f2bf(a4 * ic) | ((u32)f2bf(a5 * ic) << 16);
        o.w = (u32)f2bf(a6 * ic) | ((u32)f2bf(a7 * ic) << 16);
        *reinterpret_cast<uint4*>(outA + (size_t)node * D + r * 8) = o;
    }
}

// ---------------- gather mean, 64-wide rows (bf16) — layer-2 path ----------------
__global__ __launch_bounds__(256) void gather64_kernel(const u16* __restrict__ yin,
        const int* __restrict__ rowptr, const int* __restrict__ colidx,
        const float* __restrict__ invd, u16* __restrict__ outM, int N) {
    const int node = blockIdx.x * 4 + (threadIdx.x >> 6);
    if (node >= N) return;
    const int lane = threadIdx.x & 63;
    const int g = lane >> 4;
    const int r = lane & 15;          // bf16 cols [r*4, r*4+4)
    const int beg = rowptr[node];
    const int nb = rowptr[node + 1] - beg;

    float a0 = 0.f, a1 = 0.f, a2 = 0.f, a3 = 0.f;

    for (int base = 0; base < nb; base += 8) {
        const bool p0 = (base + g) < nb;
        const bool p1 = (base + 4 + g) < nb;
        uint2 v0 = make_uint2(0, 0), v1 = v0;
        if (p0) {
            int s0 = colidx[beg + base + g];
            v0 = *reinterpret_cast<const uint2*>(yin + (size_t)s0 * 64 + r * 4);
        }
        if (p1) {
            int s1 = colidx[beg + base + 4 + g];
            v1 = *reinterpret_cast<const uint2*>(yin + (size_t)s1 * 64 + r * 4);
        }
        a0 += bf2f((u16)v0.x) + bf2f((u16)v1.x);
        a1 += bf2f((u16)(v0.x >> 16)) + bf2f((u16)(v1.x >> 16));
        a2 += bf2f((u16)v0.y) + bf2f((u16)v1.y);
        a3 += bf2f((u16)(v0.y >> 16)) + bf2f((u16)(v1.y >> 16));
    }

    #pragma unroll
    for (int m = 16; m <= 32; m <<= 1) {
        a0 += __shfl_xor(a0, m, 64); a1 += __shfl_xor(a1, m, 64);
        a2 += __shfl_xor(a2, m, 64); a3 += __shfl_xor(a3, m, 64);
    }

    if (g == 0) {
        const float ic = invd[node];
        uint2 o;
        o.x = (u32)f2bf(a0 * ic) | ((u32)f2bf(a1 * ic) << 16);
        o.y = (u32)f2bf(a2 * ic) | ((u32)f2bf(a3 * ic) << 16);
        *reinterpret_cast<uint2*>(outM + (size_t)node * 64 + r * 4) = o;
    }
}

// ---------------- dual MFMA GEMM: out = [mean|x] @ [Wl|Wr]^T + b (layers 0,1) --------
template<int DOUT, bool RELU, bool BF16OUT>
__global__ __launch_bounds__(256) void sage_gemm(
    const u16* __restrict__ Abf, const u16* __restrict__ Xbf,
    const float* __restrict__ Wl, const float* __restrict__ Wr,
    const float* __restrict__ bias, float* __restrict__ outf,
    u16* __restrict__ outb, int N, int nchunks)
{
    constexpr int BM = 256;
    constexpr int NKB = 4;
    constexpr int WR = (DOUT == 128) ? 2 : 4;
    constexpr int WC = 4 / WR;
    constexpr int WTM = BM / WR;
    constexpr int WTN = DOUT / WC;
    constexpr int MR = WTM / 32;
    constexpr int NC = WTN / 32;
    constexpr int LDA = 72;
    constexpr int LDW = 264;

    __shared__ u16 sW[DOUT][LDW];
    __shared__ u16 sA[2][BM][LDA];

    const int tid = threadIdx.x;
    const int lane = tid & 63;
    const int w = tid >> 6;
    const int wr = w % WR;
    const int wc = w / WR;

    for (int i = tid; i < DOUT * 64; i += 256) {
        const int c = i >> 6, q = i & 63;
        const float* sp = (q < 32) ? (Wl + (size_t)c * 128 + q * 4)
                                   : (Wr + (size_t)c * 128 + (q - 32) * 4);
        float4 wv = *reinterpret_cast<const float4*>(sp);
        u32* dp = reinterpret_cast<u32*>(&sW[c][q * 4]);
        dp[0] = (u32)f2bf(wv.x) | ((u32)f2bf(wv.y) << 16);
        dp[1] = (u32)f2bf(wv.z) | ((u32)f2bf(wv.w) << 16);
    }

    short8 rg[2][4];

    auto STAGE = [&](int kb, int m0) {
        const u16* srcb = (kb < 2) ? Abf : Xbf;
        const int koff = (kb & 1) * 64;
        #pragma unroll
        for (int p = 0; p < 2; ++p) {
            const int r = (tid >> 1) + p * 128;
            const int row = m0 + r;
            const u16* sp = srcb + (size_t)row * D + koff + (tid & 1) * 32;
            if (row < N) {
                #pragma unroll
                for (int uu = 0; uu < 4; ++uu)
                    rg[p][uu] = *reinterpret_cast<const short8*>(sp + uu * 8);
            } else {
                #pragma unroll
                for (int uu = 0; uu < 4; ++uu) rg[p][uu] = zero8();
            }
        }
    };
    auto WLDS = [&](int buf) {
        #pragma unroll
        for (int p = 0; p < 2; ++p) {
            const int r = (tid >> 1) + p * 128;
            u16* dp = &sA[buf][r][(tid & 1) * 32];
            #pragma unroll
            for (int uu = 0; uu < 4; ++uu)
                *reinterpret_cast<short8*>(dp + uu * 8) = rg[p][uu];
        }
    };

    for (int chunk = blockIdx.x; chunk < nchunks; chunk += gridDim.x) {
        const int m0 = chunk * BM;
        STAGE(0, m0);
        __syncthreads();
        WLDS(0);

        float16 acc[MR][NC];
        #pragma unroll
        for (int mi = 0; mi < MR; ++mi)
            #pragma unroll
            for (int ni = 0; ni < NC; ++ni)
                #pragma unroll
                for (int e = 0; e < 16; ++e) acc[mi][ni][e] = 0.f;

        #pragma unroll
        for (int kb = 0; kb < NKB; ++kb) {
            if (kb + 1 < NKB) STAGE(kb + 1, m0);
            __syncthreads();
            #pragma unroll
            for (int ks = 0; ks < 4; ++ks) {
                short8 af[MR], bfv[NC];
                #pragma unroll
                for (int mi = 0; mi < MR; ++mi)
                    af[mi] = *reinterpret_cast<const short8*>(
                        &sA[kb & 1][wr * WTM + mi * 32 + (lane & 31)]
                           [ks * 16 + (lane >> 5) * 8]);
                #pragma unroll
                for (int ni = 0; ni < NC; ++ni)
                    bfv[ni] = *reinterpret_cast<const short8*>(
                        &sW[wc * WTN + ni * 32 + (lane & 31)]
                           [kb * 64 + ks * 16 + (lane >> 5) * 8]);
                #pragma unroll
                for (int mi = 0; mi < MR; ++mi)
                    #pragma unroll
                    for (int ni = 0; ni < NC; ++ni)
                        acc[mi][ni] = __builtin_amdgcn_mfma_f32_32x32x16_bf16(
                            af[mi], bfv[ni], acc[mi][ni], 0, 0, 0);
            }
            if (kb + 1 < NKB) WLDS((kb + 1) & 1);
        }

        #pragma unroll
        for (int ni = 0; ni < NC; ++ni) {
            const int col = wc * WTN + ni * 32 + (lane & 31);
            const float bv = bias[col];
            #pragma unroll
            for (int mi = 0; mi < MR; ++mi) {
                #pragma unroll
                for (int e = 0; e < 16; ++e) {
                    const int row = wr * WTM + mi * 32 + 4 * (lane >> 5)
                                    + (e & 3) + 8 * (e >> 2);
                    const int grow = m0 + row;
                    if (grow < N) {
                        float v = acc[mi][ni][e] + bv;
                        if (RELU) v = fmaxf(v, 0.f);
                        if (BF16OUT) outb[(size_t)grow * DOUT + col] = f2bf(v);
                        else         outf[(size_t)grow * DOUT + col] = v;
                    }
                }
            }
        }
    }
}

// ---------------- single-operand GEMM (DOUT=64, K=128) for layer 2 ----------------
template<bool ADDMEAN, bool BF16OUT, bool BIAS>
__global__ __launch_bounds__(256) void lin_gemm(
    const u16* __restrict__ In, const float* __restrict__ W,
    const float* __restrict__ bias, const u16* __restrict__ mean2,
    float* __restrict__ outf, u16* __restrict__ outb, int N, int nchunks)
{
    constexpr int DOUT = 64;
    constexpr int BM = 256;
    constexpr int NKB = 2;      // K=128 in 2 slices of 64
    constexpr int WTM = 64;     // 4 waves stacked on rows
    constexpr int MR = 2, NC = 2;
    constexpr int LDA = 72;
    constexpr int LDW = 136;    // 128 + 8 pad

    __shared__ u16 sW[DOUT][LDW];
    __shared__ u16 sA[2][BM][LDA];

    const int tid = threadIdx.x;
    const int lane = tid & 63;
    const int wr = tid >> 6;

    for (int i = tid; i < DOUT * 32; i += 256) {
        const int c = i >> 5, q = i & 31;
        float4 wv = *reinterpret_cast<const float4*>(W + (size_t)c * 128 + q * 4);
        u32* dp = reinterpret_cast<u32*>(&sW[c][q * 4]);
        dp[0] = (u32)f2bf(wv.x) | ((u32)f2bf(wv.y) << 16);
        dp[1] = (u32)f2bf(wv.z) | ((u32)f2bf(wv.w) << 16);
    }

    short8 rg[2][4];

    auto STAGE = [&](int kb, int m0) {
        const int koff = kb * 64;
        #pragma unroll
        for (int p = 0; p < 2; ++p) {
            const int r = (tid >> 1) + p * 128;
            const int row = m0 + r;
            const u16* sp = In + (size_t)row * D + koff + (tid & 1) * 32;
            if (row < N) {
                #pragma unroll
                for (int uu = 0; uu < 4; ++uu)
                    rg[p][uu] = *reinterpret_cast<const short8*>(sp + uu * 8);
            } else {
                #pragma unroll
                for (int uu = 0; uu < 4; ++uu) rg[p][uu] = zero8();
            }
        }
    };
    auto WLDS = [&](int buf) {
        #pragma unroll
        for (int p = 0; p < 2; ++p) {
            const int r = (tid >> 1) + p * 128;
            u16* dp = &sA[buf][r][(tid & 1) * 32];
            #pragma unroll
            for (int uu = 0; uu < 4; ++uu)
                *reinterpret_cast<short8*>(dp + uu * 8) = rg[p][uu];
        }
    };

    for (int chunk = blockIdx.x; chunk < nchunks; chunk += gridDim.x) {
        const int m0 = chunk * BM;
        STAGE(0, m0);
        __syncthreads();
        WLDS(0);

        float16 acc[MR][NC];
        #pragma unroll
        for (int mi = 0; mi < MR; ++mi)
            #pragma unroll
            for (int ni = 0; ni < NC; ++ni)
                #pragma unroll
                for (int e = 0; e < 16; ++e) acc[mi][ni][e] = 0.f;

        #pragma unroll
        for (int kb = 0; kb < NKB; ++kb) {
            if (kb + 1 < NKB) STAGE(kb + 1, m0);
            __syncthreads();
            #pragma unroll
            for (int ks = 0; ks < 4; ++ks) {
                short8 af[MR], bfv[NC];
                #pragma unroll
                for (int mi = 0; mi < MR; ++mi)
                    af[mi] = *reinterpret_cast<const short8*>(
                        &sA[kb & 1][wr * WTM + mi * 32 + (lane & 31)]
                           [ks * 16 + (lane >> 5) * 8]);
                #pragma unroll
                for (int ni = 0; ni < NC; ++ni)
                    bfv[ni] = *reinterpret_cast<const short8*>(
                        &sW[ni * 32 + (lane & 31)]
                           [kb * 64 + ks * 16 + (lane >> 5) * 8]);
                #pragma unroll
                for (int mi = 0; mi < MR; ++mi)
                    #pragma unroll
                    for (int ni = 0; ni < NC; ++ni)
                        acc[mi][ni] = __builtin_amdgcn_mfma_f32_32x32x16_bf16(
                            af[mi], bfv[ni], acc[mi][ni], 0, 0, 0);
            }
            if (kb + 1 < NKB) WLDS((kb + 1) & 1);
        }

        #pragma unroll
        for (int ni = 0; ni < NC; ++ni) {
            const int col = ni * 32 + (lane & 31);
            const float bv = BIAS ? bias[col] : 0.f;
            #pragma unroll
            for (int mi = 0; mi < MR; ++mi) {
                #pragma unroll
                for (int e = 0; e < 16; ++e) {
                    const int row = wr * WTM + mi * 32 + 4 * (lane >> 5)
                                    + (e & 3) + 8 * (e >> 2);
                    const int grow = m0 + row;
                    if (grow < N) {
                        float v = acc[mi][ni][e] + bv;
                        if (ADDMEAN) v += bf2f(mean2[(size_t)grow * 64 + col]);
                        if (BF16OUT) outb[(size_t)grow * DOUT + col] = f2bf(v);
                        else         outf[(size_t)grow * DOUT + col] = v;
                    }
                }
            }
        }
    }
}

extern "C" void kernel_launch(void* const* d_in, const int* in_sizes, int n_in,
                              void* d_out, int out_size, void* d_ws, size_t ws_size,
                              hipStream_t stream) {
    const float* x   = (const float*)d_in[0];
    const float* Wl0 = (const float*)d_in[1];
    const float* Wr0 = (const float*)d_in[2];
    const float* b0  = (const float*)d_in[3];
    const float* Wl1 = (const float*)d_in[4];
    const float* Wr1 = (const float*)d_in[5];
    const float* b1  = (const float*)d_in[6];
    const float* Wl2 = (const float*)d_in[7];
    const float* Wr2 = (const float*)d_in[8];
    const float* b2  = (const float*)d_in[9];
    const int* ei    = (const int*)d_in[10];

    const int E = in_sizes[10] / 2;
    const int N = in_sizes[0] / D;
    const int* src = ei;
    const int* dst = ei + E;

    // workspace
    u16* Xbf = (u16*)d_ws;                      // [N][128]
    u16* Abf = Xbf + (size_t)N * D;             // [N][128] mean (L0/L1); L2: y2|mean2
    u16* H0  = Abf + (size_t)N * D;             // [N][128]
    u16* H1  = H0 + (size_t)N * D;              // [N][128]
    float* invd   = (float*)(H1 + (size_t)N * D);
    int*   cntS   = (int*)(invd + N);           // [8][N] sharded histogram
    int*   off    = cntS + (size_t)NSHARD * N;  // [8][N] shard prefix
    int*   cnttot = off + (size_t)NSHARD * N;   // [N]
    int*   rowptr = cnttot + N;                 // [N+8]
    int*   blksum = rowptr + N + 8;             // [512]
    int*   colidx = blksum + 512;               // [E]
    int*   rank   = colidx + E;                 // [E]
    float* out = (float*)d_out;

    u16* y2    = Abf;                           // [N][64] (L2 transform)
    u16* mean2 = Abf + (size_t)N * 64;          // [N][64]

    const int NB = (N + 1023) / 1024;
    const int nblkA = (E + 255) / 256;
    const int n8 = N * D / 8;
    const int nblkB = (n8 + 255) / 256;

    hipMemsetAsync(cntS, 0, (size_t)NSHARD * N * sizeof(int), stream);
    hist_tobf16_kernel<<<nblkA + nblkB, 256, 0, stream>>>(
        dst, cntS, rank, E, N, nblkA, x, Xbf, n8);
    shardoff_kernel<<<(N + 255) / 256, 256, 0, stream>>>(cntS, off, cnttot, invd, N);
    scan1_kernel<<<NB, 256, 0, stream>>>(cnttot, rowptr, blksum, N);
    scan2_kernel<<<1, 256, 0, stream>>>(blksum, NB);
    scan3_kernel<<<NB, 256, 0, stream>>>(rowptr, blksum, N);
    fill_kernel <<<nblkA, 256, 0, stream>>>(src, dst, rowptr, off, rank, colidx, E, N);

    const int ggrid = (N + 3) / 4;
    const int nchunks = (N + 255) / 256;
    const int ggemm = (nchunks + 1) / 2;

    // layer 0
    gather_kernel<<<ggrid, 256, 0, stream>>>(Xbf, rowptr, colidx, invd, Abf, N);
    sage_gemm<128, true, true><<<ggemm, 256, 0, stream>>>(
        Abf, Xbf, Wl0, Wr0, b0, nullptr, H0, N, nchunks);

    // layer 1
    gather_kernel<<<ggrid, 256, 0, stream>>>(H0, rowptr, colidx, invd, Abf, N);
    sage_gemm<128, true, true><<<ggemm, 256, 0, stream>>>(
        Abf, H0, Wl1, Wr1, b1, nullptr, H1, N, nchunks);

    // layer 2: transform-before-aggregate (aggregation is linear; 64-wide gather)
    lin_gemm<false, true, false><<<ggemm, 256, 0, stream>>>(
        H1, Wl2, nullptr, nullptr, nullptr, y2, N, nchunks);
    gather64_kernel<<<ggrid, 256, 0, stream>>>(y2, rowptr, colidx, invd, mean2, N);
    lin_gemm<true, false, true><<<ggemm, 256, 0, stream>>>(
        H1, Wr2, b2, mean2, out, nullptr, N, nchunks);
}